// Round 1
// baseline (565.958 us; speedup 1.0000x reference)
//
#include <hip/hip_runtime.h>

#define ND 64
#define NS 32
#define EPS 1e-5f

// One thread per ray. Loads both 64-float rows into registers (float4),
// computes padded+normalized CDF prefix on the fly, co-walks the fixed
// midpoint u-grid against the CDF (monotone two-pointer), and emits the
// merged sorted 96-float output row in a single streaming pass.
// All register-array indices are compile-time (full unroll) to avoid scratch.
__global__ __launch_bounds__(256) void pdf_sample_kernel(
    const float* __restrict__ W,
    const float* __restrict__ O,
    float* __restrict__ out,
    int num_rays)
{
    int ray = blockIdx.x * 256 + threadIdx.x;
    if (ray >= num_rays) return;

    const float4* wrow = reinterpret_cast<const float4*>(W + (size_t)ray * ND);
    const float4* orow = reinterpret_cast<const float4*>(O + (size_t)ray * ND);

    float wr[ND];
    float od[ND];
    float s = 0.f;
    #pragma unroll
    for (int i = 0; i < ND / 4; ++i) {
        float4 w = wrow[i];
        float4 o = orow[i];
        wr[4*i+0] = w.x; wr[4*i+1] = w.y; wr[4*i+2] = w.z; wr[4*i+3] = w.w;
        od[4*i+0] = o.x; od[4*i+1] = o.y; od[4*i+2] = o.z; od[4*i+3] = o.w;
        s += (w.x + w.y) + (w.z + w.w);
    }

    float pad  = fmaxf(EPS - s, 0.f);
    float invT = 1.f / (s + pad);
    float padw = pad * (1.f / ND);

    float* outrow = out + (size_t)ray * (ND + NS);

    int   j = 0;          // next u index to consume
    int   pos = 0;        // output write position
    float P = 0.f;        // running raw-weight prefix
    float cprev = 0.f;    // cdf[k-1]

    #pragma unroll
    for (int k = 1; k <= ND; ++k) {
        P += wr[k - 1];
        float ck   = (P + (float)k * padw) * invT;      // cdf[k]
        float offl = od[k - 1];                         // off[idx_left]  = off[k-1]
        float offr = od[(k < ND) ? k : (ND - 1)];       // off[idx_right] = off[min(k,63)]
        outrow[pos++] = offl;                           // emit original sample off[k-1]
        // consume all u with searchsorted-right index == k: cdf[k-1] <= u < cdf[k]
        while (j < NS) {
            float u = ((float)j + 0.5f) * (1.f / NS);
            if (!(u < ck)) break;
            float t = (u - cprev) / (ck - cprev);       // denom > 0 on this path
            t = fminf(fmaxf(t, 0.f), 1.f);
            outrow[pos++] = fmaf(t, offr - offl, offl);
            ++j;
        }
        cprev = ck;
    }
    // any residual u (idx == 64 with rounding): reference yields off[63]
    float offlast = od[ND - 1];
    while (j < NS) { outrow[pos++] = offlast; ++j; }
}

extern "C" void kernel_launch(void* const* d_in, const int* in_sizes, int n_in,
                              void* d_out, int out_size, void* d_ws, size_t ws_size,
                              hipStream_t stream) {
    const float* W = (const float*)d_in[0];   // weights   [R, 64]
    const float* O = (const float*)d_in[1];   // s_offsets [R, 64]
    float* out = (float*)d_out;               // [R, 96]
    int num_rays = in_sizes[0] / ND;
    int blocks = (num_rays + 255) / 256;
    hipLaunchKernelGGL(pdf_sample_kernel, dim3(blocks), dim3(256), 0, stream,
                       W, O, out, num_rays);
}